// Round 3
// baseline (897.824 us; speedup 1.0000x reference)
//
#include <hip/hip_runtime.h>
#include <hip/hip_bf16.h>
#include <math.h>

#define VTAG 50257
#define EDIM 128
#define NREP 10
#define BFUNC 2048
#define NSTRIP 786          // ceil(50257/64)
#define NPAD (NSTRIP * 64)  // 50304

typedef __bf16 bf16x8 __attribute__((ext_vector_type(8)));
typedef float f32x4 __attribute__((ext_vector_type(4)));

__device__ __forceinline__ unsigned short f2bf(float x) {
    unsigned u = __float_as_uint(x);
    unsigned r = (u + 0x7fffu + ((u >> 16) & 1u)) >> 16;
    return (unsigned short)r;
}

// ---------------------------------------------------------------------------
// K1: per-function context encode + attention pool -> v (bf16) [B, E]
// block = 128 threads (thread = output channel e), grid = B
// ---------------------------------------------------------------------------
__global__ __launch_bounds__(128) void k1_attn(
    const int* __restrict__ v1i, const int* __restrict__ pti,
    const int* __restrict__ v2i,
    const float* __restrict__ vemb, const float* __restrict__ pemb,
    const float* __restrict__ Wfc, const float* __restrict__ bfc,
    const float* __restrict__ watt, const float* __restrict__ batt,
    unsigned short* __restrict__ vbf)
{
    const int b = blockIdx.x;
    const int e = threadIdx.x;              // 0..127
    __shared__ float ctx[NREP][3 * EDIM];   // 15360 B
    __shared__ float red[2][NREP];

    // cooperative gather of [10 x 384] context matrix (coalesced 128-chunks)
    #pragma unroll
    for (int j = 0; j < 30; ++j) {
        int i = j * 128 + e;
        int n = i / 384;                    // constant per j (384 = 3*128)
        int c = i - n * 384;
        float val;
        if (c < 128)      val = vemb[(size_t)v1i[b * NREP + n] * EDIM + c];
        else if (c < 256) val = pemb[(size_t)pti[b * NREP + n] * EDIM + (c - 128)];
        else              val = vemb[(size_t)v2i[b * NREP + n] * EDIM + (c - 256)];
        ctx[n][c] = val;
    }
    __syncthreads();

    // c_tilde[n][e] = tanh(b_fc[e] + sum_k ctx[n][k] * Wfc[k][e])
    float acc[NREP];
    #pragma unroll
    for (int n = 0; n < NREP; ++n) acc[n] = 0.f;

    for (int k = 0; k < 384; k += 4) {
        float w0 = Wfc[(k + 0) * EDIM + e];
        float w1 = Wfc[(k + 1) * EDIM + e];
        float w2 = Wfc[(k + 2) * EDIM + e];
        float w3 = Wfc[(k + 3) * EDIM + e];
        #pragma unroll
        for (int n = 0; n < NREP; ++n) {
            float4 c4 = *(const float4*)&ctx[n][k];
            acc[n] = fmaf(c4.x, w0, acc[n]);
            acc[n] = fmaf(c4.y, w1, acc[n]);
            acc[n] = fmaf(c4.z, w2, acc[n]);
            acc[n] = fmaf(c4.w, w3, acc[n]);
        }
    }

    const float bias = bfc[e];
    const float we = watt[e];
    float ct[NREP];
    #pragma unroll
    for (int n = 0; n < NREP; ++n) ct[n] = tanhf(acc[n] + bias);

    // attention logits: a[n] = sum_e ct[n][e] * w_att[e]  (reduce over 128 thr)
    const int wv = e >> 6, ln = e & 63;
    #pragma unroll
    for (int n = 0; n < NREP; ++n) {
        float p = ct[n] * we;
        p += __shfl_xor(p, 32);
        p += __shfl_xor(p, 16);
        p += __shfl_xor(p, 8);
        p += __shfl_xor(p, 4);
        p += __shfl_xor(p, 2);
        p += __shfl_xor(p, 1);
        if (ln == 0) red[wv][n] = p;
    }
    __syncthreads();

    const float batt0 = batt[0];
    float al[NREP];
    float m = -1e30f;
    #pragma unroll
    for (int n = 0; n < NREP; ++n) {
        al[n] = red[0][n] + red[1][n] + batt0;
        m = fmaxf(m, al[n]);
    }
    float s = 0.f;
    #pragma unroll
    for (int n = 0; n < NREP; ++n) { al[n] = __expf(al[n] - m); s += al[n]; }
    const float inv = 1.f / s;

    float v = 0.f;
    #pragma unroll
    for (int n = 0; n < NREP; ++n) v = fmaf(al[n] * inv, ct[n], v);

    vbf[b * EDIM + e] = f2bf(v);
}

// ---------------------------------------------------------------------------
// Kconv: tag_emb fp32 [VT,128] -> bf16 [NPAD,128], zero-padded rows
// ---------------------------------------------------------------------------
__global__ __launch_bounds__(256) void k_conv_tag(
    const float* __restrict__ tag, unsigned short* __restrict__ tbf)
{
    size_t i = ((size_t)blockIdx.x * 256 + threadIdx.x) * 4;
    if (i >= (size_t)NPAD * EDIM) return;
    float4 x = make_float4(0.f, 0.f, 0.f, 0.f);
    if (i < (size_t)VTAG * EDIM) x = *(const float4*)(tag + i);
    ushort4 o;
    o.x = f2bf(x.x); o.y = f2bf(x.y); o.z = f2bf(x.z); o.w = f2bf(x.w);
    *(ushort4*)(tbf + i) = o;
}

// ---------------------------------------------------------------------------
// K2: per-strip sum of exp(logit). No max subtraction: |logit| <= ~13 so
// exp never overflows fp32. block = 256 thr = 4 waves; wave covers 32 rows
// x 64 cols. grid = (B/128, NSTRIP). One coalesced 512-B store per block
// into transposed psumT[strip][row].
// ---------------------------------------------------------------------------
__global__ __launch_bounds__(256) void k2_partial(
    const unsigned short* __restrict__ vbf, const unsigned short* __restrict__ tbf,
    float* __restrict__ psumT)
{
    const int wave = threadIdx.x >> 6;
    const int lane = threadIdx.x & 63;
    const int quad = lane >> 4;
    const int l16  = lane & 15;
    const int strip = blockIdx.y;
    const int n0 = strip * 64;
    const int rowbase = blockIdx.x * 128 + wave * 32;

    __shared__ float srow[128];

    const bf16x8* tb8 = (const bf16x8*)tbf;  // unit = 16 B = 8 bf16
    const bf16x8* vb8 = (const bf16x8*)vbf;

    // B frags: lane holds tag[col = n0+nt*16+l16][k = ks*32 + quad*8 + j]
    bf16x8 bfrag[4][4];
    #pragma unroll
    for (int nt = 0; nt < 4; ++nt) {
        int col = n0 + nt * 16 + l16;
        const bf16x8* p = tb8 + (size_t)col * 16 + quad;
        #pragma unroll
        for (int ks = 0; ks < 4; ++ks) bfrag[nt][ks] = p[ks * 4];
    }
    // A frags: lane holds v[row = rowbase+mt*16+l16][k = ks*32 + quad*8 + j]
    bf16x8 afrag[2][4];
    #pragma unroll
    for (int mt = 0; mt < 2; ++mt) {
        int row = rowbase + mt * 16 + l16;
        const bf16x8* p = vb8 + (size_t)row * 16 + quad;
        #pragma unroll
        for (int ks = 0; ks < 4; ++ks) afrag[mt][ks] = p[ks * 4];
    }

    f32x4 acc[2][4];
    #pragma unroll
    for (int mt = 0; mt < 2; ++mt)
        #pragma unroll
        for (int nt = 0; nt < 4; ++nt) acc[mt][nt] = (f32x4){0.f, 0.f, 0.f, 0.f};

    #pragma unroll
    for (int ks = 0; ks < 4; ++ks)
        #pragma unroll
        for (int mt = 0; mt < 2; ++mt)
            #pragma unroll
            for (int nt = 0; nt < 4; ++nt)
                acc[mt][nt] = __builtin_amdgcn_mfma_f32_16x16x32_bf16(
                    afrag[mt][ks], bfrag[nt][ks], acc[mt][nt], 0, 0, 0);

    // D[row = quad*4 + r][col = l16] per 16x16 tile (HW-verified map)
    #pragma unroll
    for (int mt = 0; mt < 2; ++mt) {
        #pragma unroll
        for (int r = 0; r < 4; ++r) {
            float ls = 0.f;
            #pragma unroll
            for (int nt = 0; nt < 4; ++nt) {
                int col = n0 + nt * 16 + l16;
                if (col < VTAG) ls += __expf(acc[mt][nt][r]);
            }
            ls += __shfl_xor(ls, 1);
            ls += __shfl_xor(ls, 2);
            ls += __shfl_xor(ls, 4);
            ls += __shfl_xor(ls, 8);
            if (l16 == 0)
                srow[wave * 32 + mt * 16 + quad * 4 + r] = ls;
        }
    }
    __syncthreads();
    if (threadIdx.x < 128)
        psumT[(size_t)strip * BFUNC + blockIdx.x * 128 + threadIdx.x] =
            srow[threadIdx.x];
}

// ---------------------------------------------------------------------------
// K3: rowR[row] = 1 / sum_strips psumT[strip][row]
// thread = row; fully coalesced strided reads. grid = B/256.
// ---------------------------------------------------------------------------
__global__ __launch_bounds__(256) void k3_reduce(
    const float* __restrict__ psumT, float* __restrict__ rowR)
{
    const int row = blockIdx.x * 256 + threadIdx.x;
    float s0 = 0.f, s1 = 0.f, s2 = 0.f, s3 = 0.f;
    int i = 0;
    for (; i + 4 <= NSTRIP; i += 4) {
        s0 += psumT[(size_t)(i + 0) * BFUNC + row];
        s1 += psumT[(size_t)(i + 1) * BFUNC + row];
        s2 += psumT[(size_t)(i + 2) * BFUNC + row];
        s3 += psumT[(size_t)(i + 3) * BFUNC + row];
    }
    for (; i < NSTRIP; ++i) s0 += psumT[(size_t)i * BFUNC + row];
    rowR[row] = 1.f / (s0 + s1 + s2 + s3);
}

// ---------------------------------------------------------------------------
// K4: recompute logits (bit-identical MFMA tiling to K2), q = exp(x)*R[row].
// Epilogue stages the 128x64 tile in LDS, then each wave streams its 32
// rows as 256-B contiguous segments (full L2-line coverage, no half-line
// scatter).
// ---------------------------------------------------------------------------
__global__ __launch_bounds__(256) void k4_write(
    const unsigned short* __restrict__ vbf, const unsigned short* __restrict__ tbf,
    const float* __restrict__ rowR, float* __restrict__ out)
{
    const int wave = threadIdx.x >> 6;
    const int lane = threadIdx.x & 63;
    const int quad = lane >> 4;
    const int l16  = lane & 15;
    const int strip = blockIdx.y;
    const int n0 = strip * 64;
    const int rowbase = blockIdx.x * 128 + wave * 32;

    __shared__ float tile[128][65];   // pad 65 -> conflict-light write/read

    const bf16x8* tb8 = (const bf16x8*)tbf;
    const bf16x8* vb8 = (const bf16x8*)vbf;

    // hoist row scales early (independent of MFMA chain)
    float Rv[2][4];
    #pragma unroll
    for (int mt = 0; mt < 2; ++mt)
        #pragma unroll
        for (int r = 0; r < 4; ++r)
            Rv[mt][r] = rowR[rowbase + mt * 16 + quad * 4 + r];

    bf16x8 bfrag[4][4];
    #pragma unroll
    for (int nt = 0; nt < 4; ++nt) {
        int col = n0 + nt * 16 + l16;
        const bf16x8* p = tb8 + (size_t)col * 16 + quad;
        #pragma unroll
        for (int ks = 0; ks < 4; ++ks) bfrag[nt][ks] = p[ks * 4];
    }
    bf16x8 afrag[2][4];
    #pragma unroll
    for (int mt = 0; mt < 2; ++mt) {
        int row = rowbase + mt * 16 + l16;
        const bf16x8* p = vb8 + (size_t)row * 16 + quad;
        #pragma unroll
        for (int ks = 0; ks < 4; ++ks) afrag[mt][ks] = p[ks * 4];
    }

    f32x4 acc[2][4];
    #pragma unroll
    for (int mt = 0; mt < 2; ++mt)
        #pragma unroll
        for (int nt = 0; nt < 4; ++nt) acc[mt][nt] = (f32x4){0.f, 0.f, 0.f, 0.f};

    #pragma unroll
    for (int ks = 0; ks < 4; ++ks)
        #pragma unroll
        for (int mt = 0; mt < 2; ++mt)
            #pragma unroll
            for (int nt = 0; nt < 4; ++nt)
                acc[mt][nt] = __builtin_amdgcn_mfma_f32_16x16x32_bf16(
                    afrag[mt][ks], bfrag[nt][ks], acc[mt][nt], 0, 0, 0);

    // stage q-tile in LDS: tile[local_row][local_col]
    #pragma unroll
    for (int mt = 0; mt < 2; ++mt) {
        #pragma unroll
        for (int r = 0; r < 4; ++r) {
            const int lrow = wave * 32 + mt * 16 + quad * 4 + r;
            const float R = Rv[mt][r];
            #pragma unroll
            for (int nt = 0; nt < 4; ++nt)
                tile[lrow][nt * 16 + l16] = __expf(acc[mt][nt][r]) * R;
        }
    }
    __syncthreads();

    // stream out: wave w owns local rows [w*32, w*32+32); 256-B contiguous
    // per row (64 lanes x 4 B), strip 785 truncated to 17 valid cols.
    const int ncol = (n0 + 64 <= VTAG) ? 64 : (VTAG - n0);
    const int gbase = blockIdx.x * 128;
    #pragma unroll 4
    for (int rr = 0; rr < 32; ++rr) {
        const int lrow = wave * 32 + rr;
        if (lane < ncol)
            out[(size_t)(gbase + lrow) * VTAG + n0 + lane] = tile[lrow][lane];
    }
}

// ---------------------------------------------------------------------------
extern "C" void kernel_launch(void* const* d_in, const int* in_sizes, int n_in,
                              void* d_out, int out_size, void* d_ws, size_t ws_size,
                              hipStream_t stream)
{
    const int*   v1i  = (const int*)d_in[0];
    const int*   pti  = (const int*)d_in[1];
    const int*   v2i  = (const int*)d_in[2];
    const float* vemb = (const float*)d_in[3];
    const float* pemb = (const float*)d_in[4];
    const float* temb = (const float*)d_in[5];
    const float* Wfc  = (const float*)d_in[6];
    const float* bfc  = (const float*)d_in[7];
    const float* watt = (const float*)d_in[8];
    const float* batt = (const float*)d_in[9];
    float* out = (float*)d_out;

    char* ws = (char*)d_ws;
    const size_t vbf_off  = 0;                                   // 2048*128*2   = 524288
    const size_t tbf_off  = vbf_off + 524288;                    // 50304*128*2  = 12877824
    const size_t psum_off = tbf_off + 12877824;                  // 786*2048*4   = 6438912
    const size_t rowr_off = psum_off + 6438912;                  // 2048*4

    unsigned short* vbf = (unsigned short*)(ws + vbf_off);
    unsigned short* tbf = (unsigned short*)(ws + tbf_off);
    float* psumT = (float*)(ws + psum_off);
    float* rowR  = (float*)(ws + rowr_off);

    hipLaunchKernelGGL(k1_attn, dim3(BFUNC), dim3(128), 0, stream,
                       v1i, pti, v2i, vemb, pemb, Wfc, bfc, watt, batt, vbf);
    hipLaunchKernelGGL(k_conv_tag, dim3((NPAD * EDIM / 4 + 255) / 256), dim3(256),
                       0, stream, temb, tbf);
    hipLaunchKernelGGL(k2_partial, dim3(BFUNC / 128, NSTRIP), dim3(256), 0, stream,
                       vbf, tbf, psumT);
    hipLaunchKernelGGL(k3_reduce, dim3(BFUNC / 256), dim3(256), 0, stream,
                       psumT, rowR);
    hipLaunchKernelGGL(k4_write, dim3(BFUNC / 128, NSTRIP), dim3(256), 0, stream,
                       vbf, tbf, rowR, out);
}

// Round 4
// 848.362 us; speedup vs baseline: 1.0583x; 1.0583x over previous
//
#include <hip/hip_runtime.h>
#include <hip/hip_bf16.h>
#include <math.h>

#define VTAG 50257
#define EDIM 128
#define NREP 10
#define BFUNC 2048
#define NSTRIP 786          // ceil(50257/64)
#define NPAD (NSTRIP * 64)  // 50304

typedef __bf16 bf16x8 __attribute__((ext_vector_type(8)));
typedef float f32x4 __attribute__((ext_vector_type(4)));

__device__ __forceinline__ unsigned short f2bf(float x) {
    unsigned u = __float_as_uint(x);
    unsigned r = (u + 0x7fffu + ((u >> 16) & 1u)) >> 16;
    return (unsigned short)r;
}

// ---------------------------------------------------------------------------
// K1: per-function context encode + attention pool -> v (bf16) [B, E]
// block = 128 threads (thread = output channel e), grid = B
// ---------------------------------------------------------------------------
__global__ __launch_bounds__(128) void k1_attn(
    const int* __restrict__ v1i, const int* __restrict__ pti,
    const int* __restrict__ v2i,
    const float* __restrict__ vemb, const float* __restrict__ pemb,
    const float* __restrict__ Wfc, const float* __restrict__ bfc,
    const float* __restrict__ watt, const float* __restrict__ batt,
    unsigned short* __restrict__ vbf)
{
    const int b = blockIdx.x;
    const int e = threadIdx.x;              // 0..127
    __shared__ float ctx[NREP][3 * EDIM];   // 15360 B
    __shared__ float red[2][NREP];

    // cooperative gather of [10 x 384] context matrix (coalesced 128-chunks)
    #pragma unroll
    for (int j = 0; j < 30; ++j) {
        int i = j * 128 + e;
        int n = i / 384;                    // constant per j (384 = 3*128)
        int c = i - n * 384;
        float val;
        if (c < 128)      val = vemb[(size_t)v1i[b * NREP + n] * EDIM + c];
        else if (c < 256) val = pemb[(size_t)pti[b * NREP + n] * EDIM + (c - 128)];
        else              val = vemb[(size_t)v2i[b * NREP + n] * EDIM + (c - 256)];
        ctx[n][c] = val;
    }
    __syncthreads();

    // c_tilde[n][e] = tanh(b_fc[e] + sum_k ctx[n][k] * Wfc[k][e])
    float acc[NREP];
    #pragma unroll
    for (int n = 0; n < NREP; ++n) acc[n] = 0.f;

    for (int k = 0; k < 384; k += 4) {
        float w0 = Wfc[(k + 0) * EDIM + e];
        float w1 = Wfc[(k + 1) * EDIM + e];
        float w2 = Wfc[(k + 2) * EDIM + e];
        float w3 = Wfc[(k + 3) * EDIM + e];
        #pragma unroll
        for (int n = 0; n < NREP; ++n) {
            float4 c4 = *(const float4*)&ctx[n][k];
            acc[n] = fmaf(c4.x, w0, acc[n]);
            acc[n] = fmaf(c4.y, w1, acc[n]);
            acc[n] = fmaf(c4.z, w2, acc[n]);
            acc[n] = fmaf(c4.w, w3, acc[n]);
        }
    }

    const float bias = bfc[e];
    const float we = watt[e];
    float ct[NREP];
    #pragma unroll
    for (int n = 0; n < NREP; ++n) ct[n] = tanhf(acc[n] + bias);

    // attention logits: a[n] = sum_e ct[n][e] * w_att[e]  (reduce over 128 thr)
    const int wv = e >> 6, ln = e & 63;
    #pragma unroll
    for (int n = 0; n < NREP; ++n) {
        float p = ct[n] * we;
        p += __shfl_xor(p, 32);
        p += __shfl_xor(p, 16);
        p += __shfl_xor(p, 8);
        p += __shfl_xor(p, 4);
        p += __shfl_xor(p, 2);
        p += __shfl_xor(p, 1);
        if (ln == 0) red[wv][n] = p;
    }
    __syncthreads();

    const float batt0 = batt[0];
    float al[NREP];
    float m = -1e30f;
    #pragma unroll
    for (int n = 0; n < NREP; ++n) {
        al[n] = red[0][n] + red[1][n] + batt0;
        m = fmaxf(m, al[n]);
    }
    float s = 0.f;
    #pragma unroll
    for (int n = 0; n < NREP; ++n) { al[n] = __expf(al[n] - m); s += al[n]; }
    const float inv = 1.f / s;

    float v = 0.f;
    #pragma unroll
    for (int n = 0; n < NREP; ++n) v = fmaf(al[n] * inv, ct[n], v);

    vbf[b * EDIM + e] = f2bf(v);
}

// ---------------------------------------------------------------------------
// Kconv: tag_emb fp32 [VT,128] -> bf16 [NPAD,128], zero-padded rows
// ---------------------------------------------------------------------------
__global__ __launch_bounds__(256) void k_conv_tag(
    const float* __restrict__ tag, unsigned short* __restrict__ tbf)
{
    size_t i = ((size_t)blockIdx.x * 256 + threadIdx.x) * 4;
    if (i >= (size_t)NPAD * EDIM) return;
    float4 x = make_float4(0.f, 0.f, 0.f, 0.f);
    if (i < (size_t)VTAG * EDIM) x = *(const float4*)(tag + i);
    ushort4 o;
    o.x = f2bf(x.x); o.y = f2bf(x.y); o.z = f2bf(x.z); o.w = f2bf(x.w);
    *(ushort4*)(tbf + i) = o;
}

// ---------------------------------------------------------------------------
// K2: logits via bf16 MFMA 16x16x32; stores exp(logit) (un-normalized q) to
// out and per-strip row-sums to transposed psumT[strip][row]. No max
// subtraction: |logit| <= ~13 so exp never overflows fp32 (validated R3,
// absmax 1.19e-7). block = 256 thr = 4 waves; wave = 32 rows x 64 cols.
// grid = (B/128, NSTRIP).
// ---------------------------------------------------------------------------
__global__ __launch_bounds__(256) void k2_expstore(
    const unsigned short* __restrict__ vbf, const unsigned short* __restrict__ tbf,
    float* __restrict__ out, float* __restrict__ psumT)
{
    const int wave = threadIdx.x >> 6;
    const int lane = threadIdx.x & 63;
    const int quad = lane >> 4;
    const int l16  = lane & 15;
    const int strip = blockIdx.y;
    const int n0 = strip * 64;
    const int rowbase = blockIdx.x * 128 + wave * 32;

    __shared__ float srow[128];

    const bf16x8* tb8 = (const bf16x8*)tbf;  // unit = 16 B = 8 bf16
    const bf16x8* vb8 = (const bf16x8*)vbf;

    // B frags: lane holds tag[col = n0+nt*16+l16][k = ks*32 + quad*8 + j]
    bf16x8 bfrag[4][4];
    #pragma unroll
    for (int nt = 0; nt < 4; ++nt) {
        int col = n0 + nt * 16 + l16;
        const bf16x8* p = tb8 + (size_t)col * 16 + quad;
        #pragma unroll
        for (int ks = 0; ks < 4; ++ks) bfrag[nt][ks] = p[ks * 4];
    }
    // A frags: lane holds v[row = rowbase+mt*16+l16][k = ks*32 + quad*8 + j]
    bf16x8 afrag[2][4];
    #pragma unroll
    for (int mt = 0; mt < 2; ++mt) {
        int row = rowbase + mt * 16 + l16;
        const bf16x8* p = vb8 + (size_t)row * 16 + quad;
        #pragma unroll
        for (int ks = 0; ks < 4; ++ks) afrag[mt][ks] = p[ks * 4];
    }

    f32x4 acc[2][4];
    #pragma unroll
    for (int mt = 0; mt < 2; ++mt)
        #pragma unroll
        for (int nt = 0; nt < 4; ++nt) acc[mt][nt] = (f32x4){0.f, 0.f, 0.f, 0.f};

    #pragma unroll
    for (int ks = 0; ks < 4; ++ks)
        #pragma unroll
        for (int mt = 0; mt < 2; ++mt)
            #pragma unroll
            for (int nt = 0; nt < 4; ++nt)
                acc[mt][nt] = __builtin_amdgcn_mfma_f32_16x16x32_bf16(
                    afrag[mt][ks], bfrag[nt][ks], acc[mt][nt], 0, 0, 0);

    // epilogue: D[row = quad*4 + r][col = l16] per 16x16 tile (HW-verified)
    // store exp(x); consecutive nt stores cover consecutive 64-B sectors of
    // the same rows, so L2 sector-merges into full lines.
    #pragma unroll
    for (int mt = 0; mt < 2; ++mt) {
        #pragma unroll
        for (int r = 0; r < 4; ++r) {
            const int row = rowbase + mt * 16 + quad * 4 + r;
            float ls = 0.f;
            #pragma unroll
            for (int nt = 0; nt < 4; ++nt) {
                int col = n0 + nt * 16 + l16;
                if (col < VTAG) {
                    float ex = __expf(acc[mt][nt][r]);
                    ls += ex;
                    out[(size_t)row * VTAG + col] = ex;
                }
            }
            ls += __shfl_xor(ls, 1);
            ls += __shfl_xor(ls, 2);
            ls += __shfl_xor(ls, 4);
            ls += __shfl_xor(ls, 8);
            if (l16 == 0)
                srow[wave * 32 + mt * 16 + quad * 4 + r] = ls;
        }
    }
    __syncthreads();
    if (threadIdx.x < 128)
        psumT[(size_t)strip * BFUNC + blockIdx.x * 128 + threadIdx.x] =
            srow[threadIdx.x];
}

// ---------------------------------------------------------------------------
// K3: rowR[row] = 1 / sum_strips psumT[strip][row]
// thread = row; coalesced strided reads; unroll x8 for MLP (only 8 blocks
// -> 1 wave/SIMD, per-thread outstanding loads are the latency hiding).
// ---------------------------------------------------------------------------
__global__ __launch_bounds__(256) void k3_reduce(
    const float* __restrict__ psumT, float* __restrict__ rowR)
{
    const int row = blockIdx.x * 256 + threadIdx.x;
    float s0 = 0.f, s1 = 0.f, s2 = 0.f, s3 = 0.f;
    float s4 = 0.f, s5 = 0.f, s6 = 0.f, s7 = 0.f;
    int i = 0;
    for (; i + 8 <= NSTRIP; i += 8) {
        s0 += psumT[(size_t)(i + 0) * BFUNC + row];
        s1 += psumT[(size_t)(i + 1) * BFUNC + row];
        s2 += psumT[(size_t)(i + 2) * BFUNC + row];
        s3 += psumT[(size_t)(i + 3) * BFUNC + row];
        s4 += psumT[(size_t)(i + 4) * BFUNC + row];
        s5 += psumT[(size_t)(i + 5) * BFUNC + row];
        s6 += psumT[(size_t)(i + 6) * BFUNC + row];
        s7 += psumT[(size_t)(i + 7) * BFUNC + row];
    }
    for (; i < NSTRIP; ++i) s0 += psumT[(size_t)i * BFUNC + row];
    rowR[row] = 1.f / (((s0 + s1) + (s2 + s3)) + ((s4 + s5) + (s6 + s7)));
}

// ---------------------------------------------------------------------------
// K4: pure streaming scale: q = x * R[row]. flat float4 (16B-aligned);
// row via constant division. No exp, no max -- BW-only.
// ---------------------------------------------------------------------------
__global__ __launch_bounds__(256) void k4_scale(
    float* __restrict__ out, const float* __restrict__ rowR)
{
    unsigned i0 = (blockIdx.x * 256u + threadIdx.x) * 4u;
    const unsigned total = (unsigned)BFUNC * VTAG;
    if (i0 >= total) return;
    unsigned row = i0 / VTAG;                 // compile-time magic div
    unsigned c = i0 - row * VTAG;
    if (c + 4 <= VTAG) {
        float R = rowR[row];
        float4 x = *(float4*)(out + i0);
        x.x *= R; x.y *= R; x.z *= R; x.w *= R;
        *(float4*)(out + i0) = x;
    } else {
        #pragma unroll
        for (int j = 0; j < 4; ++j) {
            unsigned i = i0 + j;
            unsigned r2 = i / VTAG;
            out[i] *= rowR[r2];
        }
    }
}

// ---------------------------------------------------------------------------
extern "C" void kernel_launch(void* const* d_in, const int* in_sizes, int n_in,
                              void* d_out, int out_size, void* d_ws, size_t ws_size,
                              hipStream_t stream)
{
    const int*   v1i  = (const int*)d_in[0];
    const int*   pti  = (const int*)d_in[1];
    const int*   v2i  = (const int*)d_in[2];
    const float* vemb = (const float*)d_in[3];
    const float* pemb = (const float*)d_in[4];
    const float* temb = (const float*)d_in[5];
    const float* Wfc  = (const float*)d_in[6];
    const float* bfc  = (const float*)d_in[7];
    const float* watt = (const float*)d_in[8];
    const float* batt = (const float*)d_in[9];
    float* out = (float*)d_out;

    char* ws = (char*)d_ws;
    const size_t vbf_off  = 0;                                   // 2048*128*2   = 524288
    const size_t tbf_off  = vbf_off + 524288;                    // 50304*128*2  = 12877824
    const size_t psum_off = tbf_off + 12877824;                  // 786*2048*4   = 6438912
    const size_t rowr_off = psum_off + 6438912;                  // 2048*4

    unsigned short* vbf = (unsigned short*)(ws + vbf_off);
    unsigned short* tbf = (unsigned short*)(ws + tbf_off);
    float* psumT = (float*)(ws + psum_off);
    float* rowR  = (float*)(ws + rowr_off);

    hipLaunchKernelGGL(k1_attn, dim3(BFUNC), dim3(128), 0, stream,
                       v1i, pti, v2i, vemb, pemb, Wfc, bfc, watt, batt, vbf);
    hipLaunchKernelGGL(k_conv_tag, dim3((NPAD * EDIM / 4 + 255) / 256), dim3(256),
                       0, stream, temb, tbf);
    hipLaunchKernelGGL(k2_expstore, dim3(BFUNC / 128, NSTRIP), dim3(256), 0, stream,
                       vbf, tbf, out, psumT);
    hipLaunchKernelGGL(k3_reduce, dim3(BFUNC / 256), dim3(256), 0, stream,
                       psumT, rowR);
    hipLaunchKernelGGL(k4_scale, dim3(((unsigned)BFUNC * VTAG / 4 + 255) / 256),
                       dim3(256), 0, stream, out, rowR);
}